// Round 19
// baseline (109.822 us; speedup 1.0000x reference)
//
#include <hip/hip_runtime.h>
#include <hip/hip_bf16.h>

#define LATN 512
#define FINN 256
#define FOUTN 256
#define NB 16
#define HH 64
#define WW 64

typedef __attribute__((ext_vector_type(8))) short bf16x8;
typedef __attribute__((ext_vector_type(4))) float f32x4;
typedef __attribute__((ext_vector_type(4))) int i32x4;

// ------- workspace byte offsets -------
#define WS_MW2    4096        // 256*256*4 = 262144
#define WS_DCO    266240      // 16*256*4  = 16384
#define WS_STY    282624      // 16*256*4  = 16384 (NOT aliased with xm)
#define WS_WFMT   299008      // 4*294912  = 1179648
#define WS_XM     1478656     // 16*2097152 = 33554432
// style ping-pong buffers ALIAS the xm region (dead before xcvt writes xm):
#define WS_HA     (WS_XM)            // 16*512*4
#define WS_HB     (WS_XM + 32768)    // 16*512*4
// xm layout  : [b][chunk(8)][pos(4096)][slot(4)] granules of 16B (8 bf16 ch), slot = iq ^ sigma(h,w)
// wfmt layout: [obi(4)][chunk(8)][tap(9)][ol(64)][slot(4)] granules, slot = iq ^ ((ol>>1)&3)

// ================= weight prep: swizzled wfmt + mw2 =================
__global__ void weight_prep_kernel(const float* __restrict__ weight,
                                   __hip_bfloat16* __restrict__ wfmt,
                                   float* __restrict__ mw2sum) {
    __shared__ float red[256];
    int o = blockIdx.x, t = threadIdx.x;
    const float* wrow = weight + ((size_t)o * FINN + t) * 9;
    float wv[9];
    float mx = 0.f;
    #pragma unroll
    for (int k = 0; k < 9; ++k) { wv[k] = wrow[k]; mx = fmaxf(mx, fabsf(wv[k])); }
    red[t] = mx;
    __syncthreads();
    for (int k = 128; k > 0; k >>= 1) {
        if (t < k) red[t] = fmaxf(red[t], red[t + k]);
        __syncthreads();
    }
    float scale = (1.0f / 48.0f) / red[0];
    int obi = o >> 6, ol = o & 63, ch = t >> 5, il = t & 31;
    int slot = (il >> 3) ^ ((ol >> 1) & 3);
    char* basep = (char*)wfmt + (size_t)obi * 294912 + (size_t)ch * 36864
                + (size_t)ol * 64 + slot * 16 + (il & 7) * 2;
    float s2 = 0.f;
    #pragma unroll
    for (int tap = 0; tap < 9; ++tap) {
        float m = wv[tap] * scale;
        s2 += m * m;
        *(__hip_bfloat16*)(basep + tap * 4096) = __float2bfloat16(m);
    }
    mw2sum[(size_t)o * FINN + t] = s2;
}

// ================= style MLP layer (parallel over j across blocks) =================
__global__ __launch_bounds__(256) void style_layer_kernel(
    const float* __restrict__ in, const float* __restrict__ w,
    const float* __restrict__ bias, float* __restrict__ out,
    int in_dim_v4, int out_dim, float scale, int do_lrelu) {
    int t = threadIdx.x;
    int jl = t >> 4, kl = t & 15;
    int j = blockIdx.x * 16 + jl;
    int b = blockIdx.y;
    const float4* inr = (const float4*)(in + (size_t)b * (in_dim_v4 * 4));
    const float4* wr  = (const float4*)(w + (size_t)j * (in_dim_v4 * 4));
    float sum = 0.f;
    #pragma unroll 4
    for (int kb = kl; kb < in_dim_v4; kb += 16) {
        float4 wv = wr[kb], iv = inr[kb];
        sum += wv.x * iv.x + wv.y * iv.y + wv.z * iv.z + wv.w * iv.w;
    }
    #pragma unroll
    for (int off = 8; off >= 1; off >>= 1)
        sum += __shfl_xor(sum, off, 16);
    if (kl == 0) {
        float v = sum * scale + bias[j];
        if (do_lrelu && v < 0.f) v *= 0.2f;
        out[(size_t)b * out_dim + j] = v;
    }
}

// ================= x NCHW fp32 -> swizzled chunk-major bf16 xm =================
// inf-norm fused (wave-redundant shfl); blocks h<4 also emit dcoef for o-quarter h.
__global__ __launch_bounds__(256) void xcvt_kernel(const float* __restrict__ x,
                                                   const float* __restrict__ sty,
                                                   const float* __restrict__ mw2,
                                                   float* __restrict__ dco,
                                                   char* __restrict__ xm) {
    __shared__ float tile[64][65];
    __shared__ float styl[256];
    int h = blockIdx.x, b = blockIdx.y;
    int t = threadIdx.x;
    int lane = t & 63;
    int wl_ = t & 63, ig = t >> 6;
    const float* styb = sty + (size_t)b * FINN;
    float mxv = 0.f;
    #pragma unroll
    for (int q = 0; q < 4; ++q) mxv = fmaxf(mxv, fabsf(styb[lane + 64 * q]));
    #pragma unroll
    for (int off = 32; off >= 1; off >>= 1) mxv = fmaxf(mxv, __shfl_xor(mxv, off));
    float inv_m = 1.0f / mxv;
    styl[t] = styb[t] * inv_m;
    __syncthreads();

    // dcoef for o in [h*64, h*64+64): only 4 of 64 h-blocks per b (1x redundancy)
    if (h < 4) {
        int o_l = t >> 2, kl = t & 3;
        int o = h * 64 + o_l;
        const float4* m2r = (const float4*)(mw2 + (size_t)o * FINN) + kl * 16;
        const float4* svr = (const float4*)styl + kl * 16;
        float sum = 0.f;
        #pragma unroll
        for (int kb = 0; kb < 16; ++kb) {
            float4 a = m2r[kb], v = svr[kb];
            sum += a.x * v.x * v.x + a.y * v.y * v.y + a.z * v.z * v.z + a.w * v.w * v.w;
        }
        sum += __shfl_xor(sum, 1);
        sum += __shfl_xor(sum, 2);
        if (kl == 0) dco[(size_t)b * FOUTN + o] = rsqrtf(sum + 1e-8f);
    }

    char* xmb = xm + (size_t)b * 2097152;
    for (int icb = 0; icb < 4; ++icb) {
        if (icb) __syncthreads();
        #pragma unroll
        for (int p = 0; p < 16; ++p) {
            int i_l = p * 4 + ig;
            int i = icb * 64 + i_l;
            tile[i_l][wl_] = x[((size_t)(b * FINN + i)) * 4096 + h * 64 + wl_] * styl[i];
        }
        __syncthreads();
        #pragma unroll
        for (int rep = 0; rep < 2; ++rep) {
            int g = rep * 256 + t;     // 0..511
            int w = g >> 3, q8 = g & 7;
            int chunk = icb * 2 + (q8 >> 2), iq = q8 & 3;
            int slot = iq ^ (((h + 1) + ((w + 1) >> 1)) & 3);
            short tmp[8];
            #pragma unroll
            for (int j = 0; j < 8; ++j) {
                __hip_bfloat16 hb = __float2bfloat16(tile[q8 * 8 + j][w]);
                tmp[j] = *(short*)&hb;
            }
            char* dst = xmb + (size_t)chunk * 262144 + (size_t)(h * 64 + w) * 64 + slot * 16;
            *(bf16x8*)dst = *(bf16x8*)tmp;
        }
    }
}

// ================= global_load_lds helper =================
__device__ __forceinline__ void gl_lds16(const void* g, void* l) {
    __builtin_amdgcn_global_load_lds(
        (const __attribute__((address_space(1))) unsigned int*)g,
        (__attribute__((address_space(3))) unsigned int*)l, 16, 0, 0);
}

// ---- tap with cross-kh row reuse: rb[kw] carries input row (2wid+kh) frags ----
// Per tap: 4 wf reads + 4 nb reads (+4 ra reads only at kh==0). Row_a MFMAs wait
// only on wf (row_a already in regs for kh>0) while nb's reads fly underneath.
template<int KH, int KW>
__device__ __forceinline__ void do_tap(f32x4 acc[4][8], bf16x8 rb[3][4],
                                       const char* xs, const char* wl,
                                       int wid, int l15, int lg, int wfrag) {
    constexpr int tap = KH * 3 + KW;
    bf16x8 wf[4], ra[4], nb[4];
    #pragma unroll
    for (int mt = 0; mt < 4; ++mt)
        wf[mt] = *(const bf16x8*)(wl + tap * 4096 + mt * 1024 + wfrag);
    if (KH == 0) {
        int p0 = (wid * 2) * 66 + KW + l15;
        int ba = p0 * 64 + ((lg ^ ((p0 >> 1) & 3)) << 4);
        #pragma unroll
        for (int nt = 0; nt < 4; ++nt)
            ra[nt] = *(const bf16x8*)(xs + ba + nt * 1024);
    }
    {
        int p1 = (wid * 2 + KH + 1) * 66 + KW + l15;
        int bb = p1 * 64 + ((lg ^ ((p1 >> 1) & 3)) << 4);
        #pragma unroll
        for (int nt = 0; nt < 4; ++nt)
            nb[nt] = *(const bf16x8*)(xs + bb + nt * 1024);
    }
    __builtin_amdgcn_sched_barrier(0);
    asm volatile("s_waitcnt lgkmcnt(4)" ::: "memory");  // wf (+ra) done; nb in flight
    __builtin_amdgcn_sched_barrier(0);
    __builtin_amdgcn_s_setprio(1);
    #pragma unroll
    for (int mt = 0; mt < 4; ++mt)
        #pragma unroll
        for (int nt = 0; nt < 4; ++nt)
            acc[mt][nt] = __builtin_amdgcn_mfma_f32_16x16x32_bf16(
                wf[mt], (KH == 0) ? ra[nt] : rb[KW][nt], acc[mt][nt], 0, 0, 0);
    __builtin_amdgcn_s_setprio(0);
    __builtin_amdgcn_sched_barrier(0);
    asm volatile("s_waitcnt lgkmcnt(0)" ::: "memory");  // nb ready
    __builtin_amdgcn_sched_barrier(0);
    __builtin_amdgcn_s_setprio(1);
    #pragma unroll
    for (int mt = 0; mt < 4; ++mt)
        #pragma unroll
        for (int nt = 0; nt < 4; ++nt)
            acc[mt][4 + nt] = __builtin_amdgcn_mfma_f32_16x16x32_bf16(
                wf[mt], nb[nt], acc[mt][4 + nt], 0, 0, 0);
    __builtin_amdgcn_s_setprio(0);
    #pragma unroll
    for (int nt = 0; nt < 4; ++nt) rb[KW][nt] = nb[nt];   // becomes row_a of kh+1
}

// ================= MFMA conv: 4-wave blocks, 2 blocks/CU, x-read dedup =================
// grid (8 htile, 4 obi, 16 b) = 512 blocks, 256 threads (4 waves).
// Block: 8 output rows (2/wave) x 64 o x 64 w. LDS = 79.1KB -> 2 blocks/CU.
// LDS-read dedup: tap kh's row_b == tap (kh+1)'s row_a (same kw, same address) ->
// carried in rb[3][4] regs. 84 ds_read_b128/chunk/wave instead of 108 (-22%).
__global__ __launch_bounds__(256, 2) void mconv_kernel(
    const char* __restrict__ xm, const char* __restrict__ wfmt,
    const float* __restrict__ dco, float* __restrict__ y) {
    __shared__ char xs[42240];   // 10 rows x 66 cols x 64B, swizzled slots
    __shared__ char wl[36864];   // [tap 9][o 64][slot 4] granules

    int t = threadIdx.x;
    int lane = t & 63;
    int wid = t >> 6;            // 0..3
    int h0 = blockIdx.x * 8;
    int obi = blockIdx.y;
    int b = blockIdx.z;

    // zero halo columns (c=0,65) for rows 0..9; never staged
    if (t < 80) {
        int r = t >> 3, sub = t & 7;
        int col = (sub >> 2) * 65, slot = sub & 3;
        *(i32x4*)(xs + ((r * 66 + col) * 4 + slot) * 16) = (i32x4){0, 0, 0, 0};
    }
    // zero out-of-range full rows (r=0 at htile 0; r=9 at htile 7); staging skips them
    if (h0 == 0) {
        int e = t;  // 256 threads, 256 granules
        *(i32x4*)(xs + ((0 * 66 + 1 + (e >> 2)) * 4 + (e & 3)) * 16) = (i32x4){0, 0, 0, 0};
    }
    if (h0 == 56) {
        int e = t;
        *(i32x4*)(xs + ((9 * 66 + 1 + (e >> 2)) * 4 + (e & 3)) * 16) = (i32x4){0, 0, 0, 0};
    }

    // x staging: 40 issues/chunk (10 rows x 4 quarters), 10 per wave.
    // Wave-uniform offsets -> SGPRs via readfirstlane; invalid rows = sentinel.
    const char* xmb = xm + (size_t)b * 2097152 + lane * 16;
    unsigned xoff[10], xdst[10];
    #pragma unroll
    for (int q = 0; q < 10; ++q) {
        int idx = wid * 10 + q;
        int r = idx >> 2, quarter = idx & 3;
        int gh = h0 - 1 + r;
        bool v = (gh >= 0) && (gh < HH);
        xoff[q] = (unsigned)__builtin_amdgcn_readfirstlane(
            v ? (int)((gh * 64 + quarter * 16) * 64) : (int)0xFFFFFFFF);
        xdst[q] = (unsigned)__builtin_amdgcn_readfirstlane(
            (int)((r * 66 + 1) * 64 + quarter * 1024));
    }
    // w staging: 36 issues/chunk, 9 per wave
    const char* wlane = wfmt + (size_t)obi * 294912 + lane * 16;

    f32x4 acc[4][8] = {};
    int l15 = lane & 15, lg = lane >> 4;
    int wfrag = l15 * 64 + ((lg ^ ((l15 >> 1) & 3)) << 4);

    for (int ch = 0; ch < 8; ++ch) {
        // ---- stage x + w for this chunk ----
        const char* xch = xmb + (size_t)ch * 262144;
        #pragma unroll
        for (int q = 0; q < 10; ++q)
            if (xoff[q] != 0xFFFFFFFFu) gl_lds16(xch + xoff[q], xs + xdst[q]);
        const char* wch = wlane + (size_t)ch * 36864;
        #pragma unroll
        for (int q = 0; q < 9; ++q)
            gl_lds16(wch + (wid + q * 4) * 1024, wl + (wid + q * 4) * 1024);
        asm volatile("s_waitcnt vmcnt(0) lgkmcnt(0)" ::: "memory");
        __builtin_amdgcn_s_barrier();
        __builtin_amdgcn_sched_barrier(0);

        // ---- compute: 9 taps with cross-kh x-fragment reuse ----
        {
            bf16x8 rb[3][4];
            do_tap<0, 0>(acc, rb, xs, wl, wid, l15, lg, wfrag);
            do_tap<0, 1>(acc, rb, xs, wl, wid, l15, lg, wfrag);
            do_tap<0, 2>(acc, rb, xs, wl, wid, l15, lg, wfrag);
            do_tap<1, 0>(acc, rb, xs, wl, wid, l15, lg, wfrag);
            do_tap<1, 1>(acc, rb, xs, wl, wid, l15, lg, wfrag);
            do_tap<1, 2>(acc, rb, xs, wl, wid, l15, lg, wfrag);
            do_tap<2, 0>(acc, rb, xs, wl, wid, l15, lg, wfrag);
            do_tap<2, 1>(acc, rb, xs, wl, wid, l15, lg, wfrag);
            do_tap<2, 2>(acc, rb, xs, wl, wid, l15, lg, wfrag);
        }

        __builtin_amdgcn_s_barrier();   // release xs/wl for next chunk's stage
        __builtin_amdgcn_sched_barrier(0);
    }

    // epilogue: demod + store (2 rows per wave)
    const float* dcb = dco + (size_t)b * FOUTN + obi * 64;
    #pragma unroll
    for (int rr = 0; rr < 2; ++rr) {
        float* yb = y + (((size_t)b * FOUTN + obi * 64) * HH + (h0 + wid * 2 + rr)) * WW;
        #pragma unroll
        for (int mt = 0; mt < 4; ++mt) {
            #pragma unroll
            for (int j = 0; j < 4; ++j) {
                int o_l = mt * 16 + lg * 4 + j;
                float d = dcb[o_l];
                #pragma unroll
                for (int n4 = 0; n4 < 4; ++n4)
                    yb[(size_t)o_l * 4096 + n4 * 16 + l15] = acc[mt][rr * 4 + n4][j] * d;
            }
        }
    }
}

extern "C" void kernel_launch(void* const* d_in, const int* in_sizes, int n_in,
                              void* d_out, int out_size, void* d_ws, size_t ws_size,
                              hipStream_t stream) {
    const float* x      = (const float*)d_in[0];
    const float* lat    = (const float*)d_in[1];
    const float* weight = (const float*)d_in[2];
    const float* wsm    = (const float*)d_in[3];
    const float* bsm    = (const float*)d_in[4];
    const float* wff    = (const float*)d_in[5];
    const float* bff    = (const float*)d_in[6];
    float* y = (float*)d_out;

    char* base = (char*)d_ws;
    float* mw2     = (float*)(base + WS_MW2);
    float* dco     = (float*)(base + WS_DCO);
    float* sty     = (float*)(base + WS_STY);
    __hip_bfloat16* wfmt = (__hip_bfloat16*)(base + WS_WFMT);
    char* xm       = base + WS_XM;
    float* hA      = (float*)(base + WS_HA);
    float* hB      = (float*)(base + WS_HB);

    const float eq = 0.044194173824159216f;  // 1/sqrt(512)

    weight_prep_kernel<<<FOUTN, 256, 0, stream>>>(weight, wfmt, mw2);
    style_layer_kernel<<<dim3(LATN / 16, NB), 256, 0, stream>>>(
        lat, wsm + 0 * (size_t)LATN * LATN, bsm + 0 * LATN, hA, LATN / 4, LATN, eq, 1);
    style_layer_kernel<<<dim3(LATN / 16, NB), 256, 0, stream>>>(
        hA, wsm + 1 * (size_t)LATN * LATN, bsm + 1 * LATN, hB, LATN / 4, LATN, eq, 1);
    style_layer_kernel<<<dim3(LATN / 16, NB), 256, 0, stream>>>(
        hB, wsm + 2 * (size_t)LATN * LATN, bsm + 2 * LATN, hA, LATN / 4, LATN, eq, 1);
    style_layer_kernel<<<dim3(LATN / 16, NB), 256, 0, stream>>>(
        hA, wsm + 3 * (size_t)LATN * LATN, bsm + 3 * LATN, hB, LATN / 4, LATN, eq, 1);
    style_layer_kernel<<<dim3(FINN / 16, NB), 256, 0, stream>>>(
        hB, wff, bff, sty, LATN / 4, FINN, 1.0f, 0);
    // x conversion with fused inf-norm + dcoef (h<4 blocks)
    xcvt_kernel<<<dim3(HH, NB), 256, 0, stream>>>(x, sty, mw2, dco, xm);
    // MFMA conv with x-read dedup
    mconv_kernel<<<dim3(8, 4, NB), 256, 0, stream>>>(xm, (const char*)wfmt, dco, y);
}

// Round 20
// 108.662 us; speedup vs baseline: 1.0107x; 1.0107x over previous
//
#include <hip/hip_runtime.h>
#include <hip/hip_bf16.h>

#define LATN 512
#define FINN 256
#define FOUTN 256
#define NB 16
#define HH 64
#define WW 64

typedef __attribute__((ext_vector_type(8))) short bf16x8;
typedef __attribute__((ext_vector_type(4))) float f32x4;
typedef __attribute__((ext_vector_type(4))) int i32x4;

// ------- workspace byte offsets -------
#define WS_MW2    4096        // 256*256*4 = 262144
#define WS_DCO    266240      // 16*256*4  = 16384
#define WS_STY    282624      // 16*256*4  = 16384
#define WS_WFMT   299008      // 4*294912  = 1179648
#define WS_XM     1478656     // style ping-pong + snorm live here (xm itself is gone)
#define WS_HA     (WS_XM)            // 16*512*4
#define WS_HB     (WS_XM + 32768)    // 16*512*4
#define WS_SNORM  (WS_XM + 65536)    // 16*256*4 (hA/hB dead before norm_dcoef writes)
// wfmt layout: [obi(4)][chunk(8)][tap(9)][ol(64)][slot(4)] granules, slot = iq ^ ((ol>>1)&3)

// ================= weight prep: swizzled wfmt + mw2 =================
__global__ void weight_prep_kernel(const float* __restrict__ weight,
                                   __hip_bfloat16* __restrict__ wfmt,
                                   float* __restrict__ mw2sum) {
    __shared__ float red[256];
    int o = blockIdx.x, t = threadIdx.x;
    const float* wrow = weight + ((size_t)o * FINN + t) * 9;
    float wv[9];
    float mx = 0.f;
    #pragma unroll
    for (int k = 0; k < 9; ++k) { wv[k] = wrow[k]; mx = fmaxf(mx, fabsf(wv[k])); }
    red[t] = mx;
    __syncthreads();
    for (int k = 128; k > 0; k >>= 1) {
        if (t < k) red[t] = fmaxf(red[t], red[t + k]);
        __syncthreads();
    }
    float scale = (1.0f / 48.0f) / red[0];
    int obi = o >> 6, ol = o & 63, ch = t >> 5, il = t & 31;
    int slot = (il >> 3) ^ ((ol >> 1) & 3);
    char* basep = (char*)wfmt + (size_t)obi * 294912 + (size_t)ch * 36864
                + (size_t)ol * 64 + slot * 16 + (il & 7) * 2;
    float s2 = 0.f;
    #pragma unroll
    for (int tap = 0; tap < 9; ++tap) {
        float m = wv[tap] * scale;
        s2 += m * m;
        *(__hip_bfloat16*)(basep + tap * 4096) = __float2bfloat16(m);
    }
    mw2sum[(size_t)o * FINN + t] = s2;
}

// ================= style MLP layer (parallel over j across blocks) =================
__global__ __launch_bounds__(256) void style_layer_kernel(
    const float* __restrict__ in, const float* __restrict__ w,
    const float* __restrict__ bias, float* __restrict__ out,
    int in_dim_v4, int out_dim, float scale, int do_lrelu) {
    int t = threadIdx.x;
    int jl = t >> 4, kl = t & 15;
    int j = blockIdx.x * 16 + jl;
    int b = blockIdx.y;
    const float4* inr = (const float4*)(in + (size_t)b * (in_dim_v4 * 4));
    const float4* wr  = (const float4*)(w + (size_t)j * (in_dim_v4 * 4));
    float sum = 0.f;
    #pragma unroll 4
    for (int kb = kl; kb < in_dim_v4; kb += 16) {
        float4 wv = wr[kb], iv = inr[kb];
        sum += wv.x * iv.x + wv.y * iv.y + wv.z * iv.z + wv.w * iv.w;
    }
    #pragma unroll
    for (int off = 8; off >= 1; off >>= 1)
        sum += __shfl_xor(sum, off, 16);
    if (kl == 0) {
        float v = sum * scale + bias[j];
        if (do_lrelu && v < 0.f) v *= 0.2f;
        out[(size_t)b * out_dim + j] = v;
    }
}

// ================= fused inf-norm + dcoef (R14-proven, 16 blocks) =================
__global__ __launch_bounds__(256) void norm_dcoef_kernel(
    const float* __restrict__ sty, const float* __restrict__ mw2,
    float* __restrict__ snorm, float* __restrict__ dco) {
    __shared__ float red[256];
    __shared__ float s2[256];
    int b = blockIdx.x, t = threadIdx.x;
    float v = sty[(size_t)b * FINN + t];
    red[t] = fabsf(v);
    __syncthreads();
    for (int k = 128; k > 0; k >>= 1) {
        if (t < k) red[t] = fmaxf(red[t], red[t + k]);
        __syncthreads();
    }
    float sv = v / red[0];
    snorm[(size_t)b * FINN + t] = sv;
    s2[t] = sv * sv;
    __syncthreads();
    const float4* m2 = (const float4*)(mw2 + (size_t)t * FINN);
    const float4* sq = (const float4*)s2;
    float sum = 0.f;
    #pragma unroll 8
    for (int kb = 0; kb < 64; ++kb) {
        float4 a = m2[kb], xq = sq[kb];
        sum += a.x * xq.x + a.y * xq.y + a.z * xq.z + a.w * xq.w;
    }
    dco[(size_t)b * FOUTN + t] = rsqrtf(sum + 1e-8f);
}

// ================= global_load_lds helper =================
__device__ __forceinline__ void gl_lds16(const void* g, void* l) {
    __builtin_amdgcn_global_load_lds(
        (const __attribute__((address_space(1))) unsigned int*)g,
        (__attribute__((address_space(3))) unsigned int*)l, 16, 0, 0);
}

// ---- tap with cross-kh row reuse: rb[kw] carries input row (2wid+kh) frags ----
template<int KH, int KW>
__device__ __forceinline__ void do_tap(f32x4 acc[4][8], bf16x8 rb[3][4],
                                       const char* xs, const char* wl,
                                       int wid, int l15, int lg, int wfrag) {
    constexpr int tap = KH * 3 + KW;
    bf16x8 wf[4], ra[4], nb[4];
    #pragma unroll
    for (int mt = 0; mt < 4; ++mt)
        wf[mt] = *(const bf16x8*)(wl + tap * 4096 + mt * 1024 + wfrag);
    if (KH == 0) {
        int p0 = (wid * 2) * 66 + KW + l15;
        int ba = p0 * 64 + ((lg ^ ((p0 >> 1) & 3)) << 4);
        #pragma unroll
        for (int nt = 0; nt < 4; ++nt)
            ra[nt] = *(const bf16x8*)(xs + ba + nt * 1024);
    }
    {
        int p1 = (wid * 2 + KH + 1) * 66 + KW + l15;
        int bb = p1 * 64 + ((lg ^ ((p1 >> 1) & 3)) << 4);
        #pragma unroll
        for (int nt = 0; nt < 4; ++nt)
            nb[nt] = *(const bf16x8*)(xs + bb + nt * 1024);
    }
    __builtin_amdgcn_sched_barrier(0);
    asm volatile("s_waitcnt lgkmcnt(4)" ::: "memory");  // wf (+ra) done; nb in flight
    __builtin_amdgcn_sched_barrier(0);
    __builtin_amdgcn_s_setprio(1);
    #pragma unroll
    for (int mt = 0; mt < 4; ++mt)
        #pragma unroll
        for (int nt = 0; nt < 4; ++nt)
            acc[mt][nt] = __builtin_amdgcn_mfma_f32_16x16x32_bf16(
                wf[mt], (KH == 0) ? ra[nt] : rb[KW][nt], acc[mt][nt], 0, 0, 0);
    __builtin_amdgcn_s_setprio(0);
    __builtin_amdgcn_sched_barrier(0);
    asm volatile("s_waitcnt lgkmcnt(0)" ::: "memory");  // nb ready
    __builtin_amdgcn_sched_barrier(0);
    __builtin_amdgcn_s_setprio(1);
    #pragma unroll
    for (int mt = 0; mt < 4; ++mt)
        #pragma unroll
        for (int nt = 0; nt < 4; ++nt)
            acc[mt][4 + nt] = __builtin_amdgcn_mfma_f32_16x16x32_bf16(
                wf[mt], nb[nt], acc[mt][4 + nt], 0, 0, 0);
    __builtin_amdgcn_s_setprio(0);
    #pragma unroll
    for (int nt = 0; nt < 4; ++nt) rb[KW][nt] = nb[nt];   // becomes row_a of kh+1
}

// ================= MFMA conv: direct-x staging (xcvt eliminated) =================
// grid (8 htile, 4 obi, 16 b) = 512 blocks, 256 threads (4 waves).
// Block: 8 output rows (2/wave) x 64 o x 64 w. LDS = 42.2K(xs)+36.9K(wl)+1K(styl)
// = 80.1KB -> 2 blocks/CU. Staging converts fp32 NCHW x in-kernel: wave wid owns
// i-quarter wid; per row, 8 coalesced dword loads (256B/wave each), style-mul,
// pack bf16x8, one swizzled ds_write_b128 (per-lane ds_write has no layout
// restriction, unlike global_load_lds). Weights still via global_load_lds.
__global__ __launch_bounds__(256, 2) void mconv_kernel(
    const float* __restrict__ x, const char* __restrict__ wfmt,
    const float* __restrict__ snorm, const float* __restrict__ dco,
    float* __restrict__ y) {
    __shared__ char xs[42240];   // 10 rows x 66 cols x 64B, swizzled slots
    __shared__ char wl[36864];   // [tap 9][o 64][slot 4] granules
    __shared__ float styl[256];

    int t = threadIdx.x;
    int lane = t & 63;           // = w for staging
    int wid = t >> 6;            // 0..3 = i-quarter for staging
    int h0 = blockIdx.x * 8;
    int obi = blockIdx.y;
    int b = blockIdx.z;

    // zero halo columns (c=0,65) for rows 0..9; never written by staging
    if (t < 80) {
        int r = t >> 3, sub = t & 7;
        int col = (sub >> 2) * 65, slot = sub & 3;
        *(i32x4*)(xs + ((r * 66 + col) * 4 + slot) * 16) = (i32x4){0, 0, 0, 0};
    }
    // normalized styles into LDS (used during staging of every chunk)
    styl[t] = snorm[(size_t)b * FINN + t];
    __syncthreads();

    // w staging base
    const char* wlane = wfmt + (size_t)obi * 294912 + lane * 16;
    const float* xbb = x + (size_t)b * FINN * 4096;

    f32x4 acc[4][8] = {};
    int l15 = lane & 15, lg = lane >> 4;
    int wfrag = l15 * 64 + ((lg ^ ((l15 >> 1) & 3)) << 4);

    for (int ch = 0; ch < 8; ++ch) {
        // ---- w staging (DMA) ----
        const char* wch = wlane + (size_t)ch * 36864;
        #pragma unroll
        for (int q = 0; q < 9; ++q)
            gl_lds16(wch + (wid + q * 4) * 1024, wl + (wid + q * 4) * 1024);

        // ---- x staging: direct fp32 load + style-mul + bf16 pack + swizzled write ----
        {
            float sv[8];
            #pragma unroll
            for (int j = 0; j < 8; ++j) sv[j] = styl[ch * 32 + wid * 8 + j];
            const float* xq = xbb + (size_t)(ch * 32 + wid * 8) * 4096;
            #pragma unroll
            for (int r = 0; r < 10; ++r) {
                int gh = h0 - 1 + r;
                short tmp[8];
                if (gh >= 0 && gh < HH) {
                    #pragma unroll
                    for (int j = 0; j < 8; ++j) {
                        float v = xq[(size_t)j * 4096 + gh * 64 + lane] * sv[j];
                        __hip_bfloat16 hb = __float2bfloat16(v);
                        tmp[j] = *(short*)&hb;
                    }
                } else {
                    #pragma unroll
                    for (int j = 0; j < 8; ++j) tmp[j] = 0;
                }
                int s = wid ^ (((gh + 1) + ((lane + 1) >> 1)) & 3);
                *(bf16x8*)(xs + (r * 66 + 1 + lane) * 64 + s * 16) = *(bf16x8*)tmp;
            }
        }
        asm volatile("s_waitcnt vmcnt(0) lgkmcnt(0)" ::: "memory");
        __builtin_amdgcn_s_barrier();
        __builtin_amdgcn_sched_barrier(0);

        // ---- compute: 9 taps with cross-kh x-fragment reuse ----
        {
            bf16x8 rb[3][4];
            do_tap<0, 0>(acc, rb, xs, wl, wid, l15, lg, wfrag);
            do_tap<0, 1>(acc, rb, xs, wl, wid, l15, lg, wfrag);
            do_tap<0, 2>(acc, rb, xs, wl, wid, l15, lg, wfrag);
            do_tap<1, 0>(acc, rb, xs, wl, wid, l15, lg, wfrag);
            do_tap<1, 1>(acc, rb, xs, wl, wid, l15, lg, wfrag);
            do_tap<1, 2>(acc, rb, xs, wl, wid, l15, lg, wfrag);
            do_tap<2, 0>(acc, rb, xs, wl, wid, l15, lg, wfrag);
            do_tap<2, 1>(acc, rb, xs, wl, wid, l15, lg, wfrag);
            do_tap<2, 2>(acc, rb, xs, wl, wid, l15, lg, wfrag);
        }

        __builtin_amdgcn_s_barrier();   // release xs/wl for next chunk's stage
        __builtin_amdgcn_sched_barrier(0);
    }

    // epilogue: demod + store (2 rows per wave)
    const float* dcb = dco + (size_t)b * FOUTN + obi * 64;
    #pragma unroll
    for (int rr = 0; rr < 2; ++rr) {
        float* yb = y + (((size_t)b * FOUTN + obi * 64) * HH + (h0 + wid * 2 + rr)) * WW;
        #pragma unroll
        for (int mt = 0; mt < 4; ++mt) {
            #pragma unroll
            for (int j = 0; j < 4; ++j) {
                int o_l = mt * 16 + lg * 4 + j;
                float d = dcb[o_l];
                #pragma unroll
                for (int n4 = 0; n4 < 4; ++n4)
                    yb[(size_t)o_l * 4096 + n4 * 16 + l15] = acc[mt][rr * 4 + n4][j] * d;
            }
        }
    }
}

extern "C" void kernel_launch(void* const* d_in, const int* in_sizes, int n_in,
                              void* d_out, int out_size, void* d_ws, size_t ws_size,
                              hipStream_t stream) {
    const float* x      = (const float*)d_in[0];
    const float* lat    = (const float*)d_in[1];
    const float* weight = (const float*)d_in[2];
    const float* wsm    = (const float*)d_in[3];
    const float* bsm    = (const float*)d_in[4];
    const float* wff    = (const float*)d_in[5];
    const float* bff    = (const float*)d_in[6];
    float* y = (float*)d_out;

    char* base = (char*)d_ws;
    float* mw2     = (float*)(base + WS_MW2);
    float* dco     = (float*)(base + WS_DCO);
    float* sty     = (float*)(base + WS_STY);
    __hip_bfloat16* wfmt = (__hip_bfloat16*)(base + WS_WFMT);
    float* hA      = (float*)(base + WS_HA);
    float* hB      = (float*)(base + WS_HB);
    float* snorm   = (float*)(base + WS_SNORM);

    const float eq = 0.044194173824159216f;  // 1/sqrt(512)

    weight_prep_kernel<<<FOUTN, 256, 0, stream>>>(weight, wfmt, mw2);
    style_layer_kernel<<<dim3(LATN / 16, NB), 256, 0, stream>>>(
        lat, wsm + 0 * (size_t)LATN * LATN, bsm + 0 * LATN, hA, LATN / 4, LATN, eq, 1);
    style_layer_kernel<<<dim3(LATN / 16, NB), 256, 0, stream>>>(
        hA, wsm + 1 * (size_t)LATN * LATN, bsm + 1 * LATN, hB, LATN / 4, LATN, eq, 1);
    style_layer_kernel<<<dim3(LATN / 16, NB), 256, 0, stream>>>(
        hB, wsm + 2 * (size_t)LATN * LATN, bsm + 2 * LATN, hA, LATN / 4, LATN, eq, 1);
    style_layer_kernel<<<dim3(LATN / 16, NB), 256, 0, stream>>>(
        hA, wsm + 3 * (size_t)LATN * LATN, bsm + 3 * LATN, hB, LATN / 4, LATN, eq, 1);
    style_layer_kernel<<<dim3(FINN / 16, NB), 256, 0, stream>>>(
        hB, wff, bff, sty, LATN / 4, FINN, 1.0f, 0);
    norm_dcoef_kernel<<<NB, 256, 0, stream>>>(sty, mw2, snorm, dco);
    // MFMA conv with direct-x staging (xcvt pass eliminated)
    mconv_kernel<<<dim3(8, 4, NB), 256, 0, stream>>>(x, (const char*)wfmt, snorm, dco, y);
}